// Round 9
// baseline (201.472 us; speedup 1.0000x reference)
//
#include <hip/hip_runtime.h>

typedef unsigned short u16;
typedef __attribute__((ext_vector_type(8))) short short8;
typedef __attribute__((ext_vector_type(4))) float f32x4;

__device__ __forceinline__ u16 f2b(float f) {
  union { float f; unsigned u; } v; v.f = f;
  unsigned u = v.u;
  return (u16)((u + 0x7FFFu + ((u >> 16) & 1u)) >> 16);
}
__device__ __forceinline__ u16 f2b_trunc(float f) {
  union { float f; unsigned u; } v; v.f = f;
  return (u16)(v.u >> 16);
}
// async global->LDS, 16B per lane; LDS base must be wave-uniform (lane scatters +lane*16B)
__device__ __forceinline__ void glds16(const u16* g, u16* l) {
  __builtin_amdgcn_global_load_lds((const __attribute__((address_space(1))) void*)g,
                                   (__attribute__((address_space(3))) void*)l, 16, 0, 0);
}

// ---------------- fused prep: 5x fp32->bf16 convert + cos/sin table + C zero-init ----
// blocks [0,8192): convert x/wq/wk/wv/wo to bf16
// blocks [8192,8448): interleaved cos/sin table
// blocks [8448,12544): zero the fp32 output C (split-K bt accumulates via atomicAdd)
__global__ __launch_bounds__(256) void prep_k(const float* __restrict__ x,
                                              const float* __restrict__ wq,
                                              const float* __restrict__ wk,
                                              const float* __restrict__ wv,
                                              const float* __restrict__ wo,
                                              const int* __restrict__ pos,
                                              u16* __restrict__ xb,
                                              u16* __restrict__ wqkvb,
                                              u16* __restrict__ wob,
                                              float* __restrict__ cs,
                                              float* __restrict__ out) {
  int bx = blockIdx.x, tid = threadIdx.x;
  if (bx < 8192) {
    const float* src; u16* dst; int base;
    if (bx < 4096)      { src = x;  dst = xb;                base = bx; }
    else if (bx < 5120) { src = wq; dst = wqkvb;             base = bx - 4096; }
    else if (bx < 6144) { src = wk; dst = wqkvb + (1 << 20); base = bx - 5120; }
    else if (bx < 7168) { src = wv; dst = wqkvb + (2 << 20); base = bx - 6144; }
    else                { src = wo; dst = wob;               base = bx - 7168; }
    int i4 = base * 1024 + tid * 4;
    const float4 v = *(const float4*)(src + i4);
    uint2 o;
    o.x = (unsigned)f2b(v.x) | ((unsigned)f2b(v.y) << 16);
    o.y = (unsigned)f2b(v.z) | ((unsigned)f2b(v.w) << 16);
    *(uint2*)(dst + i4) = o;
  } else if (bx < 8448) {
    int idx = (bx - 8192) * 256 + tid;  // S*32 = 65536
    int i = idx & 31, s = idx >> 5;
    float p = (float)pos[s];
    float inv = expf(-(float)i * (logf(10000.0f) / 32.0f));
    float ang = p * inv;
    cs[idx * 2]     = cosf(ang);
    cs[idx * 2 + 1] = sinf(ang);
  } else {
    // zero C: 4096 blocks x 256 threads x 16B = 16.8 MB (BS*D fp32)
    int i4 = (bx - 8448) * 1024 + tid * 4;
    *(float4*)(out + i4) = (float4){0.f, 0.f, 0.f, 0.f};
  }
}

// ---------------- gemm1 fused: C = xb @ wqkv^T, epilogue RoPE + head-major scatter ----
// 128x128 tile, BK=64, 256 threads = 4 waves (2x2), single-buffered (best: 44.4us).
// T1 XCD column-chunk swizzle: linear block id lin -> XCD (lin&7) owns column-tiles
// 3*(lin&7)..+2 for all 32 rows (768%8==0, bijective). B-slab per XCD = 768 KB ->
// L2-resident; A streams once via shared L3.
// Q outputs pre-scaled by 1/sqrt(dk)*log2(e) so attention uses raw exp2.
__global__ __launch_bounds__(256, 3) void gemm_qkv(const u16* __restrict__ A,
                                                   const u16* __restrict__ B,
                                                   const float* __restrict__ cs,
                                                   u16* __restrict__ Qr,
                                                   u16* __restrict__ Kr,
                                                   u16* __restrict__ VTg) {
  const int K = 1024;
  __shared__ u16 As[128 * 64];   // 16 KB
  __shared__ u16 Bs[128 * 64];   // 16 KB
  const int tid = threadIdx.x;
  const int lane = tid & 63;
  const int wvid = tid >> 6;
  const int wr = wvid >> 1, wc = wvid & 1;
  const int quad = lane >> 4, l16 = lane & 15;
  // XCD-aware bijective remap (grid 24x32 = 768 blocks, 768%8==0)
  const int lin = blockIdx.x + blockIdx.y * 24;
  const int chunk = lin >> 3;                      // 0..95
  const int ncol = (lin & 7) * 3 + (chunk % 3);    // 0..23: 3 contiguous cols per XCD
  const int nrow = chunk / 3;                      // 0..31
  const int m0 = nrow * 128, n0 = ncol * 128;
  const int sw = l16 & 7;  // row&7 for all frag rows (row = base + i*16 + l16, base%64==0)

  f32x4 acc[4][4];
  for (int i = 0; i < 4; i++)
    for (int j = 0; j < 4; j++) acc[i][j] = (f32x4){0.f, 0.f, 0.f, 0.f};

  for (int kt = 0; kt < K; kt += 64) {
    __syncthreads();
#pragma unroll
    for (int p = 0; p < 4; p++) {  // A: 1024 chunks of 16B (128 rows x 64 k)
      int c = p * 256 + tid;
      int row = c >> 3, k8 = (c & 7) ^ (row & 7);
      glds16(A + (size_t)(m0 + row) * K + kt + k8 * 8, As + (size_t)(c & ~63) * 8);
    }
#pragma unroll
    for (int p = 0; p < 4; p++) {  // B: 1024 chunks
      int c = p * 256 + tid;
      int row = c >> 3, k8 = (c & 7) ^ (row & 7);
      glds16(B + (size_t)(n0 + row) * K + kt + k8 * 8, Bs + (size_t)(c & ~63) * 8);
    }
    __syncthreads();
#pragma unroll
    for (int half = 0; half < 2; half++) {
      short8 af[4], bfr[4];
      const int kc = ((half * 4 + quad) ^ sw) * 8;
#pragma unroll
      for (int i = 0; i < 4; i++)
        af[i] = *(const short8*)(As + (wr * 64 + i * 16 + l16) * 64 + kc);
#pragma unroll
      for (int j = 0; j < 4; j++)
        bfr[j] = *(const short8*)(Bs + (wc * 64 + j * 16 + l16) * 64 + kc);
#pragma unroll
      for (int i = 0; i < 4; i++)
#pragma unroll
        for (int j = 0; j < 4; j++)
          acc[i][j] = __builtin_amdgcn_mfma_f32_16x16x32_bf16(af[i], bfr[j], acc[i][j], 0, 0, 0);
    }
  }

  const int region = n0 >> 10;  // 0=Q 1=K 2=V (uniform per block: 128 | 1024)
  const int b = m0 >> 11;       // 128-row tile never crosses batch boundary
  if (region < 2) {
    u16* dst = region ? Kr : Qr;
    const float qs = region ? 1.0f : 0.125f * 1.44269504f;  // pre-scale Q only
    const bool evn = (l16 & 1) == 0;
    for (int i = 0; i < 4; i++)
      for (int j = 0; j < 4; j++) {
        int col = n0 + wc * 64 + j * 16 + l16;
        int cq = col & 1023;
        int h = cq >> 6, d = cq & 63, ifr = (d >> 1) & 31;
        for (int r = 0; r < 4; r++) {
          int s = (m0 & 2047) + wr * 64 + i * 16 + quad * 4 + r;
          float v = acc[i][j][r];
          float vp = __shfl_xor(v, 1);  // all lanes execute (shfl before branch)
          if (evn) {                    // v = even elem, vp = odd elem
            float2 c2 = *(const float2*)(cs + (s * 32 + ifr) * 2);
            float oe = (c2.x * v - c2.y * vp) * qs;
            float oo = (c2.y * v + c2.x * vp) * qs;
            unsigned pk = (unsigned)f2b(oe) | ((unsigned)f2b(oo) << 16);
            *(unsigned*)(dst + ((size_t)(b * 16 + h) * 2048 + s) * 64 + d) = pk;
          }
        }
      }
  } else {
    for (int j = 0; j < 4; j++) {
      int col = n0 + wc * 64 + j * 16 + l16;
      int cq = col & 1023;
      int h = cq >> 6, d = cq & 63;
      u16* base = VTg + ((size_t)(b * 16 + h) * 64 + d) * 2048;
      for (int i = 0; i < 4; i++) {
        int s0 = (m0 & 2047) + wr * 64 + i * 16 + quad * 4;
        uint2 o;
        o.x = (unsigned)f2b(acc[i][j][0]) | ((unsigned)f2b(acc[i][j][1]) << 16);
        o.y = (unsigned)f2b(acc[i][j][2]) | ((unsigned)f2b(acc[i][j][3]) << 16);
        *(uint2*)(base + s0) = o;  // 4 contiguous s per store
      }
    }
  }
}

// ---------------- bf16 GEMM, fp32 out, split-K=2: 64x128 tile, BK=64, swizzled --------
// r8 budget audit: bt ~38us at 2 blk/CU (grid 512) - same starved-residency regime that
// cost qkv 68us (r2/r3). gridDim.z=2 K-halves -> 1024 blocks = 4 blk/CU (2x TLP), same
// total staged bytes; halves accumulate into pre-zeroed C via fp32 atomicAdd (one extra
// rounding, negligible). gridDim.x==8==NXCD keeps per-XCD B-panel L2-resident across z.
__global__ __launch_bounds__(256, 4) void gemm_bt_f32(const u16* __restrict__ A,
                                                      const u16* __restrict__ B,
                                                      float* __restrict__ C,
                                                      int M, int N, int K) {
  __shared__ u16 As[64 * 64];    // 8 KB
  __shared__ u16 Bs[128 * 64];   // 16 KB
  const int tid = threadIdx.x;
  const int wv = tid >> 6, lane = tid & 63;
  const int quad = lane >> 4, l16 = lane & 15;
  const int m0 = blockIdx.y * 64, n0 = blockIdx.x * 128;
  const int sw = l16 & 7;
  const int kt0 = (K >> 1) * blockIdx.z;   // this block's K-half

  f32x4 acc[4][2];
  for (int i = 0; i < 4; i++)
    for (int j = 0; j < 2; j++) acc[i][j] = (f32x4){0.f, 0.f, 0.f, 0.f};

  for (int kt = kt0; kt < kt0 + (K >> 1); kt += 64) {
    __syncthreads();
#pragma unroll
    for (int p = 0; p < 2; p++) {  // A: 512 chunks of 16B (64 rows x 64 k)
      int c = p * 256 + tid;
      int row = c >> 3, k8 = (c & 7) ^ (row & 7);
      glds16(A + (size_t)(m0 + row) * K + kt + k8 * 8, As + (size_t)(c & ~63) * 8);
    }
#pragma unroll
    for (int p = 0; p < 4; p++) {  // B: 1024 chunks (128 rows x 64 k)
      int c = p * 256 + tid;
      int row = c >> 3, k8 = (c & 7) ^ (row & 7);
      glds16(B + (size_t)(n0 + row) * K + kt + k8 * 8, Bs + (size_t)(c & ~63) * 8);
    }
    __syncthreads();
#pragma unroll
    for (int half = 0; half < 2; half++) {
      short8 af[4], bfr[2];
      const int kc = ((half * 4 + quad) ^ sw) * 8;
#pragma unroll
      for (int i = 0; i < 4; i++)
        af[i] = *(const short8*)(As + (i * 16 + l16) * 64 + kc);
#pragma unroll
      for (int j = 0; j < 2; j++)
        bfr[j] = *(const short8*)(Bs + (wv * 32 + j * 16 + l16) * 64 + kc);
#pragma unroll
      for (int i = 0; i < 4; i++)
#pragma unroll
        for (int j = 0; j < 2; j++)
          acc[i][j] = __builtin_amdgcn_mfma_f32_16x16x32_bf16(af[i], bfr[j], acc[i][j], 0, 0, 0);
    }
  }
  for (int i = 0; i < 4; i++)
    for (int j = 0; j < 2; j++) {
      int col = n0 + wv * 32 + j * 16 + l16;
      for (int r = 0; r < 4; r++) {
        int row = m0 + i * 16 + quad * 4 + r;
        atomicAdd(&C[(size_t)row * N + col], acc[i][j][r]);
      }
    }
}

// ---------------- flash attention v8 (r5 exact: best measured, no setprio) ----------------
// 512 threads = 8 waves. Waves 0-3 own q-tile A (qt=slot), waves 4-7 tile B
// (qt=31-slot); one shared double-buffered K/V sweep (stage once, compute both).
// {slot,31-slot} pairing: both co-resident blocks on a CU have >=24-iter sweeps ->
// sustained 16-wave overlap (r6: per-CU time is MAX of block sweeps, not sum).
// T5 setprio: null on this barrier-synced structure (r8) - removed.
// Q pre-scaled (gemm epilogue) -> softmax is raw exp2, no mul/clamp.
struct AttnSM {
  u16 Ks[2][8 * 512];
  u16 Vt[2][8 * 512];
  u16 Ps[2][8 * 520];
};

template <bool DIAG>
__device__ __forceinline__ void attn_tile(const u16* Ksb, const u16* Vtb, u16* Psb,
                                          short8 qa0, short8 qa1, f32x4* oacc,
                                          float* l_r, int wl, int quad, int l16) {
  const int rowbase = wl * 16 + quad * 4;
#pragma unroll
  for (int nt = 0; nt < 4; nt++) {
    f32x4 s4 = (f32x4){0.f, 0.f, 0.f, 0.f};
    short8 b0 = *(const short8*)(Ksb + quad * 512 + (nt * 16 + l16) * 8);
    short8 b1 = *(const short8*)(Ksb + (4 + quad) * 512 + (nt * 16 + l16) * 8);
    s4 = __builtin_amdgcn_mfma_f32_16x16x32_bf16(qa0, b0, s4, 0, 0, 0);
    s4 = __builtin_amdgcn_mfma_f32_16x16x32_bf16(qa1, b1, s4, 0, 0, 0);
    int col = nt * 16 + l16;
    int cp = col >> 3, co = col & 7;
#pragma unroll
    for (int r = 0; r < 4; r++) {
      float v = s4[r];
      if (DIAG && col > rowbase + r) v = -1e30f;  // exp2 -> 0
      float p = exp2f(v);
      l_r[r] += p;
      int row = rowbase + r;
      int A = (cp + 2 * (row >> 3)) & 7;
      Psb[A * 520 + row * 8 + co] = f2b_trunc(p);
    }
  }
  int mr = wl * 16 + l16;
  int A0 = (quad + 2 * (mr >> 3)) & 7;
  short8 pa0 = *(const short8*)(Psb + A0 * 520 + mr * 8);
  short8 pa1 = *(const short8*)(Psb + ((A0 + 4) & 7) * 520 + mr * 8);
  int sl0 = quad ^ (l16 & 7);
#pragma unroll
  for (int nt = 0; nt < 4; nt++) {
    int d = nt * 16 + l16;
    short8 vb0 = *(const short8*)(Vtb + d * 64 + sl0 * 8);
    short8 vb1 = *(const short8*)(Vtb + d * 64 + (sl0 ^ 4) * 8);
    oacc[nt] = __builtin_amdgcn_mfma_f32_16x16x32_bf16(pa0, vb0, oacc[nt], 0, 0, 0);
    oacc[nt] = __builtin_amdgcn_mfma_f32_16x16x32_bf16(pa1, vb1, oacc[nt], 0, 0, 0);
  }
}

__global__ __launch_bounds__(512, 4) void attn_k(const u16* __restrict__ Q,
                                                 const u16* __restrict__ K,
                                                 const u16* __restrict__ VT,
                                                 u16* __restrict__ O, int S) {
  __shared__ AttnSM sm;  // 48.25 KB
  const int tid = threadIdx.x;
  const int wv = tid >> 6, lane = tid & 63, quad = lane >> 4, l16 = lane & 15;
  const int grp = wv >> 2, wl = wv & 3;
  const int bh = blockIdx.x, slot = blockIdx.y;
  const int qtB = 31 - slot;
  const int qtMy = grp ? qtB : slot;
  const int q0My = qtMy * 64;
  const u16* Qg = Q + (size_t)bh * S * 64;
  const u16* Kg = K + (size_t)bh * S * 64;
  const u16* Vg = VT + (size_t)bh * S * 64;  // [64][S] per bh
  const int vrow_off = lane >> 3;
  const int vchunk = (lane & 7) ^ (lane >> 3);

  // direct Q A-fragment loads (Q pre-scaled by 0.125*log2e in gemm epilogue)
  const u16* qrow = Qg + (size_t)(q0My + wl * 16 + l16) * 64;
  short8 qa0 = *(const short8*)(qrow + quad * 8);
  short8 qa1 = *(const short8*)(qrow + 32 + quad * 8);

  f32x4 oacc[4];
  for (int j = 0; j < 4; j++) oacc[j] = (f32x4){0.f, 0.f, 0.f, 0.f};
  float l_r[4] = {0.f, 0.f, 0.f, 0.f};
  u16* Psb = &sm.Ps[grp][0];

  // prologue: stage tile 0 into buffer 0 (wave p stages K-plane p + V-plane p)
  glds16(Kg + (size_t)lane * 64 + wv * 8, &sm.Ks[0][wv * 512]);
  glds16(Vg + (size_t)(wv * 8 + vrow_off) * S + vchunk * 8, &sm.Vt[0][wv * 512]);

  for (int kt = 0; kt <= qtB; kt++) {
    const int cur = kt & 1;
    __syncthreads();  // buf[cur] loads drained; prev compute on buf[cur^1] done
    if (kt < qtB) {   // prefetch next tile into other buffer (overlaps compute)
      const int kn = (kt + 1) * 64;
      glds16(Kg + (size_t)(kn + lane) * 64 + wv * 8, &sm.Ks[cur ^ 1][wv * 512]);
      glds16(Vg + (size_t)(wv * 8 + vrow_off) * S + kn + vchunk * 8, &sm.Vt[cur ^ 1][wv * 512]);
    }
    if (kt < qtMy)
      attn_tile<false>(&sm.Ks[cur][0], &sm.Vt[cur][0], Psb, qa0, qa1, oacc, l_r, wl, quad, l16);
    else if (kt == qtMy)
      attn_tile<true>(&sm.Ks[cur][0], &sm.Vt[cur][0], Psb, qa0, qa1, oacc, l_r, wl, quad, l16);
  }

  // epilogue: reduce l across the 16 l16 lanes, write normalized bf16 [B,S,H,dk]
  const int b = bh >> 4, h = bh & 15;
  const bool evn = (l16 & 1) == 0;
  const int rowbase = wl * 16 + quad * 4;
#pragma unroll
  for (int r = 0; r < 4; r++) {
    l_r[r] += __shfl_xor(l_r[r], 1); l_r[r] += __shfl_xor(l_r[r], 2);
    l_r[r] += __shfl_xor(l_r[r], 4); l_r[r] += __shfl_xor(l_r[r], 8);
    l_r[r] = 1.f / l_r[r];
  }
#pragma unroll
  for (int nt = 0; nt < 4; nt++) {
    int col = nt * 16 + l16;
#pragma unroll
    for (int r = 0; r < 4; r++) {
      float v = oacc[nt][r] * l_r[r];
      float vp = __shfl_xor(v, 1);
      if (evn) {
        int s = q0My + rowbase + r;
        unsigned pk = (unsigned)f2b(v) | ((unsigned)f2b(vp) << 16);
        *(unsigned*)(O + ((size_t)(b * S + s) * 16 + h) * 64 + col) = pk;
      }
    }
  }
}

extern "C" void kernel_launch(void* const* d_in, const int* in_sizes, int n_in,
                              void* d_out, int out_size, void* d_ws, size_t ws_size,
                              hipStream_t stream) {
  const float* x  = (const float*)d_in[0];
  const int*   tp = (const int*)d_in[1];
  const float* wq = (const float*)d_in[2];
  const float* wk = (const float*)d_in[3];
  const float* wvp = (const float*)d_in[4];
  const float* wo = (const float*)d_in[5];
  float* out = (float*)d_out;

  const int S = 2048, D = 1024;
  const int BS = 2 * S;  // 4096

  // workspace overlay (MB):
  //  [0,8)    xb      prep -> gemm1
  //  [8,14)   wqkvb   prep -> gemm1
  //  [14,16)  wob     prep -> gemm2
  //  [16,16.5) cs     prep -> gemm1
  //  [17,25)  qr, [25,33) kr, [33,41) vtg   gemm1 -> attn
  //  [42,50)  ob      attn -> gemm2
  char* ws = (char*)d_ws;
  u16*   xb    = (u16*)(ws);
  u16*   wqkvb = (u16*)(ws + ((size_t)8 << 20));
  u16*   wob   = (u16*)(ws + ((size_t)14 << 20));
  float* cs    = (float*)(ws + ((size_t)16 << 20));
  u16*   qr    = (u16*)(ws + ((size_t)17 << 20));
  u16*   kr    = (u16*)(ws + ((size_t)25 << 20));
  u16*   vtg   = (u16*)(ws + ((size_t)33 << 20));
  u16*   ob    = (u16*)(ws + ((size_t)42 << 20));

  // 8192 convert + 256 cos/sin + 4096 C-zero
  prep_k<<<12544, 256, 0, stream>>>(x, wq, wk, wvp, wo, tp, xb, wqkvb, wob, cs, out);

  dim3 g1(3 * D / 128, BS / 128);
  gemm_qkv<<<g1, 256, 0, stream>>>(xb, wqkvb, cs, qr, kr, vtg);

  dim3 ga(32, 16);
  attn_k<<<ga, 512, 0, stream>>>(qr, kr, vtg, ob, S);

  dim3 g2(D / 128, BS / 64, 2);  // split-K=2: 1024 blocks = 4 blk/CU
  gemm_bt_f32<<<g2, 256, 0, stream>>>(ob, wob, out, BS, D, D);
}

// Round 10
// 178.976 us; speedup vs baseline: 1.1257x; 1.1257x over previous
//
#include <hip/hip_runtime.h>

typedef unsigned short u16;
typedef __attribute__((ext_vector_type(8))) short short8;
typedef __attribute__((ext_vector_type(4))) float f32x4;

__device__ __forceinline__ u16 f2b(float f) {
  union { float f; unsigned u; } v; v.f = f;
  unsigned u = v.u;
  return (u16)((u + 0x7FFFu + ((u >> 16) & 1u)) >> 16);
}
__device__ __forceinline__ u16 f2b_trunc(float f) {
  union { float f; unsigned u; } v; v.f = f;
  return (u16)(v.u >> 16);
}
// async global->LDS, 16B per lane; LDS base must be wave-uniform (lane scatters +lane*16B)
__device__ __forceinline__ void glds16(const u16* g, u16* l) {
  __builtin_amdgcn_global_load_lds((const __attribute__((address_space(1))) void*)g,
                                   (__attribute__((address_space(3))) void*)l, 16, 0, 0);
}

// ---------------- fused prep: 5x fp32->bf16 convert + interleaved cos/sin table ------
__global__ __launch_bounds__(256) void prep_k(const float* __restrict__ x,
                                              const float* __restrict__ wq,
                                              const float* __restrict__ wk,
                                              const float* __restrict__ wv,
                                              const float* __restrict__ wo,
                                              const int* __restrict__ pos,
                                              u16* __restrict__ xb,
                                              u16* __restrict__ wqkvb,
                                              u16* __restrict__ wob,
                                              float* __restrict__ cs) {
  int bx = blockIdx.x, tid = threadIdx.x;
  if (bx < 8192) {
    const float* src; u16* dst; int base;
    if (bx < 4096)      { src = x;  dst = xb;                base = bx; }
    else if (bx < 5120) { src = wq; dst = wqkvb;             base = bx - 4096; }
    else if (bx < 6144) { src = wk; dst = wqkvb + (1 << 20); base = bx - 5120; }
    else if (bx < 7168) { src = wv; dst = wqkvb + (2 << 20); base = bx - 6144; }
    else                { src = wo; dst = wob;               base = bx - 7168; }
    int i4 = base * 1024 + tid * 4;
    const float4 v = *(const float4*)(src + i4);
    uint2 o;
    o.x = (unsigned)f2b(v.x) | ((unsigned)f2b(v.y) << 16);
    o.y = (unsigned)f2b(v.z) | ((unsigned)f2b(v.w) << 16);
    *(uint2*)(dst + i4) = o;
  } else {
    int idx = (bx - 8192) * 256 + tid;  // S*32 = 65536
    int i = idx & 31, s = idx >> 5;
    float p = (float)pos[s];
    float inv = expf(-(float)i * (logf(10000.0f) / 32.0f));
    float ang = p * inv;
    cs[idx * 2]     = cosf(ang);
    cs[idx * 2 + 1] = sinf(ang);
  }
}

// ---------------- gemm1 fused: C = xb @ wqkv^T, epilogue RoPE + head-major scatter ----
// 128x128 tile, BK=64, 256 threads = 4 waves (2x2), single-buffered (best: 44.4us).
// T1 XCD column-chunk swizzle: linear block id lin -> XCD (lin&7) owns column-tiles
// 3*(lin&7)..+2 for all 32 rows (768%8==0, bijective). B-slab per XCD = 768 KB ->
// L2-resident; A streams once via shared L3.
// Q outputs pre-scaled by 1/sqrt(dk)*log2(e) so attention uses raw exp2.
__global__ __launch_bounds__(256, 3) void gemm_qkv(const u16* __restrict__ A,
                                                   const u16* __restrict__ B,
                                                   const float* __restrict__ cs,
                                                   u16* __restrict__ Qr,
                                                   u16* __restrict__ Kr,
                                                   u16* __restrict__ VTg) {
  const int K = 1024;
  __shared__ u16 As[128 * 64];   // 16 KB
  __shared__ u16 Bs[128 * 64];   // 16 KB
  const int tid = threadIdx.x;
  const int lane = tid & 63;
  const int wvid = tid >> 6;
  const int wr = wvid >> 1, wc = wvid & 1;
  const int quad = lane >> 4, l16 = lane & 15;
  // XCD-aware bijective remap (grid 24x32 = 768 blocks, 768%8==0)
  const int lin = blockIdx.x + blockIdx.y * 24;
  const int chunk = lin >> 3;                      // 0..95
  const int ncol = (lin & 7) * 3 + (chunk % 3);    // 0..23: 3 contiguous cols per XCD
  const int nrow = chunk / 3;                      // 0..31
  const int m0 = nrow * 128, n0 = ncol * 128;
  const int sw = l16 & 7;  // row&7 for all frag rows (row = base + i*16 + l16, base%64==0)

  f32x4 acc[4][4];
  for (int i = 0; i < 4; i++)
    for (int j = 0; j < 4; j++) acc[i][j] = (f32x4){0.f, 0.f, 0.f, 0.f};

  for (int kt = 0; kt < K; kt += 64) {
    __syncthreads();
#pragma unroll
    for (int p = 0; p < 4; p++) {  // A: 1024 chunks of 16B (128 rows x 64 k)
      int c = p * 256 + tid;
      int row = c >> 3, k8 = (c & 7) ^ (row & 7);
      glds16(A + (size_t)(m0 + row) * K + kt + k8 * 8, As + (size_t)(c & ~63) * 8);
    }
#pragma unroll
    for (int p = 0; p < 4; p++) {  // B: 1024 chunks
      int c = p * 256 + tid;
      int row = c >> 3, k8 = (c & 7) ^ (row & 7);
      glds16(B + (size_t)(n0 + row) * K + kt + k8 * 8, Bs + (size_t)(c & ~63) * 8);
    }
    __syncthreads();
#pragma unroll
    for (int half = 0; half < 2; half++) {
      short8 af[4], bfr[4];
      const int kc = ((half * 4 + quad) ^ sw) * 8;
#pragma unroll
      for (int i = 0; i < 4; i++)
        af[i] = *(const short8*)(As + (wr * 64 + i * 16 + l16) * 64 + kc);
#pragma unroll
      for (int j = 0; j < 4; j++)
        bfr[j] = *(const short8*)(Bs + (wc * 64 + j * 16 + l16) * 64 + kc);
#pragma unroll
      for (int i = 0; i < 4; i++)
#pragma unroll
        for (int j = 0; j < 4; j++)
          acc[i][j] = __builtin_amdgcn_mfma_f32_16x16x32_bf16(af[i], bfr[j], acc[i][j], 0, 0, 0);
    }
  }

  const int region = n0 >> 10;  // 0=Q 1=K 2=V (uniform per block: 128 | 1024)
  const int b = m0 >> 11;       // 128-row tile never crosses batch boundary
  if (region < 2) {
    u16* dst = region ? Kr : Qr;
    const float qs = region ? 1.0f : 0.125f * 1.44269504f;  // pre-scale Q only
    const bool evn = (l16 & 1) == 0;
    for (int i = 0; i < 4; i++)
      for (int j = 0; j < 4; j++) {
        int col = n0 + wc * 64 + j * 16 + l16;
        int cq = col & 1023;
        int h = cq >> 6, d = cq & 63, ifr = (d >> 1) & 31;
        for (int r = 0; r < 4; r++) {
          int s = (m0 & 2047) + wr * 64 + i * 16 + quad * 4 + r;
          float v = acc[i][j][r];
          float vp = __shfl_xor(v, 1);  // all lanes execute (shfl before branch)
          if (evn) {                    // v = even elem, vp = odd elem
            float2 c2 = *(const float2*)(cs + (s * 32 + ifr) * 2);
            float oe = (c2.x * v - c2.y * vp) * qs;
            float oo = (c2.y * v + c2.x * vp) * qs;
            unsigned pk = (unsigned)f2b(oe) | ((unsigned)f2b(oo) << 16);
            *(unsigned*)(dst + ((size_t)(b * 16 + h) * 2048 + s) * 64 + d) = pk;
          }
        }
      }
  } else {
    for (int j = 0; j < 4; j++) {
      int col = n0 + wc * 64 + j * 16 + l16;
      int cq = col & 1023;
      int h = cq >> 6, d = cq & 63;
      u16* base = VTg + ((size_t)(b * 16 + h) * 64 + d) * 2048;
      for (int i = 0; i < 4; i++) {
        int s0 = (m0 & 2047) + wr * 64 + i * 16 + quad * 4;
        uint2 o;
        o.x = (unsigned)f2b(acc[i][j][0]) | ((unsigned)f2b(acc[i][j][1]) << 16);
        o.y = (unsigned)f2b(acc[i][j][2]) | ((unsigned)f2b(acc[i][j][3]) << 16);
        *(uint2*)(base + s0) = o;  // 4 contiguous s per store
      }
    }
  }
}

// ---------------- plain bf16 GEMM, fp32 out: 64x128 tile, BK=64, swizzled (r5 exact) ---
// 256 threads = 4 waves; each wave owns a 64x32 sub-tile (acc 4x2). 2 blk/CU, 8 waves/CU.
// Grid (8,64): gridDim.x==8==NXCD -> each XCD owns one column panel (B slab L2-resident).
// Split-K-via-atomicAdd: tried r9, REGRESSED +15us (C RMW re-fetch ~50MB) - do not retry.
__global__ __launch_bounds__(256, 2) void gemm_bt_f32(const u16* __restrict__ A,
                                                      const u16* __restrict__ B,
                                                      float* __restrict__ C,
                                                      int M, int N, int K) {
  __shared__ u16 As[64 * 64];    // 8 KB
  __shared__ u16 Bs[128 * 64];   // 16 KB
  const int tid = threadIdx.x;
  const int wv = tid >> 6, lane = tid & 63;
  const int quad = lane >> 4, l16 = lane & 15;
  const int m0 = blockIdx.y * 64, n0 = blockIdx.x * 128;
  const int sw = l16 & 7;

  f32x4 acc[4][2];
  for (int i = 0; i < 4; i++)
    for (int j = 0; j < 2; j++) acc[i][j] = (f32x4){0.f, 0.f, 0.f, 0.f};

  for (int kt = 0; kt < K; kt += 64) {
    __syncthreads();
#pragma unroll
    for (int p = 0; p < 2; p++) {  // A: 512 chunks of 16B (64 rows x 64 k)
      int c = p * 256 + tid;
      int row = c >> 3, k8 = (c & 7) ^ (row & 7);
      glds16(A + (size_t)(m0 + row) * K + kt + k8 * 8, As + (size_t)(c & ~63) * 8);
    }
#pragma unroll
    for (int p = 0; p < 4; p++) {  // B: 1024 chunks (128 rows x 64 k)
      int c = p * 256 + tid;
      int row = c >> 3, k8 = (c & 7) ^ (row & 7);
      glds16(B + (size_t)(n0 + row) * K + kt + k8 * 8, Bs + (size_t)(c & ~63) * 8);
    }
    __syncthreads();
#pragma unroll
    for (int half = 0; half < 2; half++) {
      short8 af[4], bfr[2];
      const int kc = ((half * 4 + quad) ^ sw) * 8;
#pragma unroll
      for (int i = 0; i < 4; i++)
        af[i] = *(const short8*)(As + (i * 16 + l16) * 64 + kc);
#pragma unroll
      for (int j = 0; j < 2; j++)
        bfr[j] = *(const short8*)(Bs + (wv * 32 + j * 16 + l16) * 64 + kc);
#pragma unroll
      for (int i = 0; i < 4; i++)
#pragma unroll
        for (int j = 0; j < 2; j++)
          acc[i][j] = __builtin_amdgcn_mfma_f32_16x16x32_bf16(af[i], bfr[j], acc[i][j], 0, 0, 0);
    }
  }
  for (int i = 0; i < 4; i++)
    for (int j = 0; j < 2; j++) {
      int col = n0 + wv * 32 + j * 16 + l16;
      for (int r = 0; r < 4; r++) {
        int row = m0 + i * 16 + quad * 4 + r;
        C[(size_t)row * N + col] = acc[i][j][r];
      }
    }
}

// ---------------- flash attention v10: r5 structure + MFMA-computed softmax denom ------
// 512 threads = 8 waves. Waves 0-3 own q-tile A (qt=slot), waves 4-7 tile B
// (qt=31-slot); one shared double-buffered K/V sweep (stage once, compute both).
// {slot,31-slot} pairing: both co-resident blocks on a CU have >=24-iter sweeps ->
// sustained 16-wave overlap (r6: per-CU time is MAX of block sweeps, not sum).
// T5 setprio: null here (r8, lockstep barriers) - removed.
// NEW (v10): softmax denominator l = P*ones via MFMA (B-frag = const bf16 1.0).
// Removes 16 VALU adds/tile + the 16-lane shfl reduce in the epilogue; moves that
// work to the 86%-idle MFMA pipe (+2 MFMA/tile). Denominator now sums the SAME
// truncated-bf16 P the numerator uses (self-consistent normalization).
// Q pre-scaled (gemm epilogue) -> softmax is raw exp2, no mul/clamp.
struct AttnSM {
  u16 Ks[2][8 * 512];
  u16 Vt[2][8 * 512];
  u16 Ps[2][8 * 520];
};

template <bool DIAG>
__device__ __forceinline__ void attn_tile(const u16* Ksb, const u16* Vtb, u16* Psb,
                                          short8 qa0, short8 qa1, f32x4* oacc,
                                          f32x4& lacc, int wl, int quad, int l16) {
  const int rowbase = wl * 16 + quad * 4;
#pragma unroll
  for (int nt = 0; nt < 4; nt++) {
    f32x4 s4 = (f32x4){0.f, 0.f, 0.f, 0.f};
    short8 b0 = *(const short8*)(Ksb + quad * 512 + (nt * 16 + l16) * 8);
    short8 b1 = *(const short8*)(Ksb + (4 + quad) * 512 + (nt * 16 + l16) * 8);
    s4 = __builtin_amdgcn_mfma_f32_16x16x32_bf16(qa0, b0, s4, 0, 0, 0);
    s4 = __builtin_amdgcn_mfma_f32_16x16x32_bf16(qa1, b1, s4, 0, 0, 0);
    int col = nt * 16 + l16;
    int cp = col >> 3, co = col & 7;
#pragma unroll
    for (int r = 0; r < 4; r++) {
      float v = s4[r];
      if (DIAG && col > rowbase + r) v = -1e30f;  // exp2 -> 0
      float p = exp2f(v);
      int row = rowbase + r;
      int A = (cp + 2 * (row >> 3)) & 7;
      Psb[A * 520 + row * 8 + co] = f2b_trunc(p);
    }
  }
  int mr = wl * 16 + l16;
  int A0 = (quad + 2 * (mr >> 3)) & 7;
  short8 pa0 = *(const short8*)(Psb + A0 * 520 + mr * 8);
  short8 pa1 = *(const short8*)(Psb + ((A0 + 4) & 7) * 520 + mr * 8);
  // l = P * ones on the MFMA pipe (every D-column holds the row-sum)
  const short8 ones = (short8){(short)0x3F80, (short)0x3F80, (short)0x3F80, (short)0x3F80,
                               (short)0x3F80, (short)0x3F80, (short)0x3F80, (short)0x3F80};
  lacc = __builtin_amdgcn_mfma_f32_16x16x32_bf16(pa0, ones, lacc, 0, 0, 0);
  lacc = __builtin_amdgcn_mfma_f32_16x16x32_bf16(pa1, ones, lacc, 0, 0, 0);
  int sl0 = quad ^ (l16 & 7);
#pragma unroll
  for (int nt = 0; nt < 4; nt++) {
    int d = nt * 16 + l16;
    short8 vb0 = *(const short8*)(Vtb + d * 64 + sl0 * 8);
    short8 vb1 = *(const short8*)(Vtb + d * 64 + (sl0 ^ 4) * 8);
    oacc[nt] = __builtin_amdgcn_mfma_f32_16x16x32_bf16(pa0, vb0, oacc[nt], 0, 0, 0);
    oacc[nt] = __builtin_amdgcn_mfma_f32_16x16x32_bf16(pa1, vb1, oacc[nt], 0, 0, 0);
  }
}

__global__ __launch_bounds__(512, 4) void attn_k(const u16* __restrict__ Q,
                                                 const u16* __restrict__ K,
                                                 const u16* __restrict__ VT,
                                                 u16* __restrict__ O, int S) {
  __shared__ AttnSM sm;  // 48.25 KB
  const int tid = threadIdx.x;
  const int wv = tid >> 6, lane = tid & 63, quad = lane >> 4, l16 = lane & 15;
  const int grp = wv >> 2, wl = wv & 3;
  const int bh = blockIdx.x, slot = blockIdx.y;
  const int qtB = 31 - slot;
  const int qtMy = grp ? qtB : slot;
  const int q0My = qtMy * 64;
  const u16* Qg = Q + (size_t)bh * S * 64;
  const u16* Kg = K + (size_t)bh * S * 64;
  const u16* Vg = VT + (size_t)bh * S * 64;  // [64][S] per bh
  const int vrow_off = lane >> 3;
  const int vchunk = (lane & 7) ^ (lane >> 3);

  // direct Q A-fragment loads (Q pre-scaled by 0.125*log2e in gemm epilogue)
  const u16* qrow = Qg + (size_t)(q0My + wl * 16 + l16) * 64;
  short8 qa0 = *(const short8*)(qrow + quad * 8);
  short8 qa1 = *(const short8*)(qrow + 32 + quad * 8);

  f32x4 oacc[4];
  for (int j = 0; j < 4; j++) oacc[j] = (f32x4){0.f, 0.f, 0.f, 0.f};
  f32x4 lacc = (f32x4){0.f, 0.f, 0.f, 0.f};
  u16* Psb = &sm.Ps[grp][0];

  // prologue: stage tile 0 into buffer 0 (wave p stages K-plane p + V-plane p)
  glds16(Kg + (size_t)lane * 64 + wv * 8, &sm.Ks[0][wv * 512]);
  glds16(Vg + (size_t)(wv * 8 + vrow_off) * S + vchunk * 8, &sm.Vt[0][wv * 512]);

  for (int kt = 0; kt <= qtB; kt++) {
    const int cur = kt & 1;
    __syncthreads();  // buf[cur] loads drained; prev compute on buf[cur^1] done
    if (kt < qtB) {   // prefetch next tile into other buffer (overlaps compute)
      const int kn = (kt + 1) * 64;
      glds16(Kg + (size_t)(kn + lane) * 64 + wv * 8, &sm.Ks[cur ^ 1][wv * 512]);
      glds16(Vg + (size_t)(wv * 8 + vrow_off) * S + kn + vchunk * 8, &sm.Vt[cur ^ 1][wv * 512]);
    }
    if (kt < qtMy)
      attn_tile<false>(&sm.Ks[cur][0], &sm.Vt[cur][0], Psb, qa0, qa1, oacc, lacc, wl, quad, l16);
    else if (kt == qtMy)
      attn_tile<true>(&sm.Ks[cur][0], &sm.Vt[cur][0], Psb, qa0, qa1, oacc, lacc, wl, quad, l16);
  }

  // epilogue: l already full row-sum via ones-MFMA (identical across l16 lanes) —
  // no cross-lane reduce needed. Write normalized bf16 [B,S,H,dk].
  const int b = bh >> 4, h = bh & 15;
  const bool evn = (l16 & 1) == 0;
  const int rowbase = wl * 16 + quad * 4;
  float l_inv[4];
#pragma unroll
  for (int r = 0; r < 4; r++) l_inv[r] = 1.f / lacc[r];
#pragma unroll
  for (int nt = 0; nt < 4; nt++) {
    int col = nt * 16 + l16;
#pragma unroll
    for (int r = 0; r < 4; r++) {
      float v = oacc[nt][r] * l_inv[r];
      float vp = __shfl_xor(v, 1);
      if (evn) {
        int s = q0My + rowbase + r;
        unsigned pk = (unsigned)f2b(v) | ((unsigned)f2b(vp) << 16);
        *(unsigned*)(O + ((size_t)(b * S + s) * 16 + h) * 64 + col) = pk;
      }
    }
  }
}

extern "C" void kernel_launch(void* const* d_in, const int* in_sizes, int n_in,
                              void* d_out, int out_size, void* d_ws, size_t ws_size,
                              hipStream_t stream) {
  const float* x  = (const float*)d_in[0];
  const int*   tp = (const int*)d_in[1];
  const float* wq = (const float*)d_in[2];
  const float* wk = (const float*)d_in[3];
  const float* wvp = (const float*)d_in[4];
  const float* wo = (const float*)d_in[5];
  float* out = (float*)d_out;

  const int S = 2048, D = 1024;
  const int BS = 2 * S;  // 4096

  // workspace overlay (MB):
  //  [0,8)    xb      prep -> gemm1
  //  [8,14)   wqkvb   prep -> gemm1
  //  [14,16)  wob     prep -> gemm2
  //  [16,16.5) cs     prep -> gemm1
  //  [17,25)  qr, [25,33) kr, [33,41) vtg   gemm1 -> attn
  //  [42,50)  ob      attn -> gemm2
  char* ws = (char*)d_ws;
  u16*   xb    = (u16*)(ws);
  u16*   wqkvb = (u16*)(ws + ((size_t)8 << 20));
  u16*   wob   = (u16*)(ws + ((size_t)14 << 20));
  float* cs    = (float*)(ws + ((size_t)16 << 20));
  u16*   qr    = (u16*)(ws + ((size_t)17 << 20));
  u16*   kr    = (u16*)(ws + ((size_t)25 << 20));
  u16*   vtg   = (u16*)(ws + ((size_t)33 << 20));
  u16*   ob    = (u16*)(ws + ((size_t)42 << 20));

  prep_k<<<8448, 256, 0, stream>>>(x, wq, wk, wvp, wo, tp, xb, wqkvb, wob, cs);

  dim3 g1(3 * D / 128, BS / 128);
  gemm_qkv<<<g1, 256, 0, stream>>>(xb, wqkvb, cs, qr, kr, vtg);

  dim3 ga(32, 16);
  attn_k<<<ga, 512, 0, stream>>>(qr, kr, vtg, ob, S);

  dim3 g2(D / 128, BS / 64);
  gemm_bt_f32<<<g2, 256, 0, stream>>>(ob, wob, out, BS, D, D);
}